// Round 8
// baseline (38.458 us; speedup 1.0000x reference)
//
#include <hip/hip_runtime.h>
#include <hip/hip_fp16.h>

typedef _Float16 f16x8 __attribute__((ext_vector_type(8)));
typedef float f32x4 __attribute__((ext_vector_type(4)));

namespace {
constexpr int K = 4096;
constexpr int N = 11008;
constexpr int NC = N / 8;      // packed int32 words per K-row = 1376
constexpr int M_ROWS = 32;
constexpr int KSPLIT = 8;      // K-slices of 512 (multiple of group size 128)
constexpr int BN = 128;        // output columns per block (4 waves x 32)
}

// x (f32) -> f16 into workspace, once per call
__global__ void cvt_x_kernel(const float* __restrict__ x, _Float16* __restrict__ xh) {
  const int i = (blockIdx.x * 256 + threadIdx.x) * 8;
  const float4 v0 = *reinterpret_cast<const float4*>(x + i);
  const float4 v1 = *reinterpret_cast<const float4*>(x + i + 4);
  f16x8 h;
  h[0] = (_Float16)v0.x; h[1] = (_Float16)v0.y;
  h[2] = (_Float16)v0.z; h[3] = (_Float16)v0.w;
  h[4] = (_Float16)v1.x; h[5] = (_Float16)v1.y;
  h[6] = (_Float16)v1.z; h[7] = (_Float16)v1.w;
  *reinterpret_cast<f16x8*>(xh + i) = h;
}

// out[m][n] = bias[n]  (fresh every call; GEMM kernel accumulates on top)
__global__ void init_out_kernel(const float* __restrict__ bias, float* __restrict__ out) {
  const int n = blockIdx.x * 256 + threadIdx.x;
  out[blockIdx.y * N + n] = bias[n];
}

// Barrier-free: no LDS, no __syncthreads. Each wave owns 32 output columns
// (2 n-tiles of 16) x all 32 rows (2 m-tiles), over a 512-deep K slice.
__global__ __launch_bounds__(256) void awq_gemm_kernel(
    const int* __restrict__ qw, const int* __restrict__ qz,
    const float* __restrict__ sc, const _Float16* __restrict__ xh,
    float* __restrict__ out)
{
  const int tid  = threadIdx.x;
  const int lane = tid & 63;
  const int wid  = tid >> 6;      // wave 0..3
  const int kq   = lane >> 4;     // 0..3  (k-quarter within MFMA frag)
  const int c16  = lane & 15;     // fragment row/col index

  const int n0 = blockIdx.x * BN;

  // AWQ nibble shift for output column (n&7): 4 * AWQ_ORDER[n&7],
  // AWQ_ORDER=[0,4,1,5,2,6,3,7]  ->  sh = 4*((j>>1) + 4*(j&1))
  const int j7 = c16 & 7;
  const int sh = ((j7 >> 1) | ((j7 & 1) << 2)) << 2;

  int ncol[2], cglob[2];
#pragma unroll
  for (int t = 0; t < 2; ++t) {
    ncol[t]  = n0 + wid * 32 + t * 16 + c16;  // this lane's output column
    cglob[t] = ncol[t] >> 3;                  // packed word column (global)
  }

  const int kbeg = blockIdx.y * (K / KSPLIT);
  const _Float16* xr0 = xh + c16 * K;         // A rows for m-tile 0
  const _Float16* xr1 = xh + (c16 + 16) * K;  // A rows for m-tile 1

  f32x4 acc[2][2] = {};   // [m-tile][n-tile]

  for (int g = 0; g < (K / KSPLIT) / 128; ++g) {   // 4 quant groups per slice
    const int gk = kbeg + g * 128;
    const int gi = gk >> 7;
    float sf[2], zs[2];
#pragma unroll
    for (int t = 0; t < 2; ++t) {
      const int zq = qz[gi * NC + cglob[t]];
      sf[t] = sc[gi * N + ncol[t]];
      zs[t] = sf[t] * (float)((zq >> sh) & 15);
    }
#pragma unroll
    for (int kk = 0; kk < 4; ++kk) {               // 4 x BK=32 within the group
      const int k0 = gk + kk * 32 + kq * 8;        // this lane's 8-k base
      // A fragments: 16B direct loads (xh is L2-resident, 256 KB)
      const f16x8 a0 = *reinterpret_cast<const f16x8*>(xr0 + k0);
      const f16x8 a1 = *reinterpret_cast<const f16x8*>(xr1 + k0);
#pragma unroll
      for (int t = 0; t < 2; ++t) {
        // gather the 8 packed words first (8 independent loads in flight)
        const int* qp = qw + (long)k0 * NC + cglob[t];
        int qv[8];
#pragma unroll
        for (int j = 0; j < 8; ++j) qv[j] = qp[(long)j * NC];
        f16x8 b;   // B: col = lane&15, k = kq*8 + j
#pragma unroll
        for (int j = 0; j < 8; ++j)
          b[j] = (_Float16)fmaf((float)((qv[j] >> sh) & 15), sf[t], -zs[t]);
        acc[0][t] = __builtin_amdgcn_mfma_f32_16x16x32_f16(a0, b, acc[0][t], 0, 0, 0);
        acc[1][t] = __builtin_amdgcn_mfma_f32_16x16x32_f16(a1, b, acc[1][t], 0, 0, 0);
      }
    }
  }

  // C/D layout (m89-verified): col = lane&15, row = (lane>>4)*4 + i
#pragma unroll
  for (int mt = 0; mt < 2; ++mt)
#pragma unroll
    for (int t = 0; t < 2; ++t)
#pragma unroll
      for (int i = 0; i < 4; ++i) {
        const int row = mt * 16 + kq * 4 + i;
        atomicAdd(out + row * N + ncol[t], acc[mt][t][i]);
      }
}

extern "C" void kernel_launch(void* const* d_in, const int* in_sizes, int n_in,
                              void* d_out, int out_size, void* d_ws, size_t ws_size,
                              hipStream_t stream) {
  const float* x    = (const float*)d_in[0];
  const int* qw     = (const int*)d_in[1];
  const int* qz     = (const int*)d_in[2];
  const float* sc   = (const float*)d_in[3];   // fp16 values delivered as f32
  const float* bias = (const float*)d_in[4];   // fp16 values delivered as f32
  float* out        = (float*)d_out;
  _Float16* xh      = (_Float16*)d_ws;         // 32*4096*2 = 256 KB

  cvt_x_kernel<<<dim3((M_ROWS * K) / (256 * 8)), 256, 0, stream>>>(x, xh);
  init_out_kernel<<<dim3(N / 256, M_ROWS), 256, 0, stream>>>(bias, out);
  awq_gemm_kernel<<<dim3(N / BN, KSPLIT), 256, 0, stream>>>(qw, qz, sc, xh, out);
}

// Round 9
// 29.761 us; speedup vs baseline: 1.2922x; 1.2922x over previous
//
#include <hip/hip_runtime.h>
#include <hip/hip_fp16.h>

typedef _Float16 f16x8 __attribute__((ext_vector_type(8)));
typedef _Float16 f16x4 __attribute__((ext_vector_type(4)));
typedef _Float16 f16x2 __attribute__((ext_vector_type(2)));
typedef float f32x4 __attribute__((ext_vector_type(4)));

namespace {
constexpr int K = 4096;
constexpr int N = 11008;
constexpr int NC = N / 8;        // 1376 packed words per K-row
constexpr int M_ROWS = 32;
constexpr int KSPLIT = 8;        // 512-deep K slices
constexpr int BN = 128;          // output columns per block (4 waves x 32)
constexpr int BK = 32;           // K rows per step
constexpr int NT = (K / KSPLIT) / BK;   // 16 steps per slice
constexpr int QSTR = 34;         // LDS q-tile stride in words ([col][k], even)
constexpr int OUT_ELEMS = M_ROWS * N;   // 352256
}

// x (f32) -> f16 into workspace, once per call
__global__ void cvt_x_kernel(const float* __restrict__ x, _Float16* __restrict__ xh) {
  const int i = (blockIdx.x * 256 + threadIdx.x) * 8;
  const float4 v0 = *reinterpret_cast<const float4*>(x + i);
  const float4 v1 = *reinterpret_cast<const float4*>(x + i + 4);
  f16x8 h;
  h[0] = (_Float16)v0.x; h[1] = (_Float16)v0.y;
  h[2] = (_Float16)v0.z; h[3] = (_Float16)v0.w;
  h[4] = (_Float16)v1.x; h[5] = (_Float16)v1.y;
  h[6] = (_Float16)v1.z; h[7] = (_Float16)v1.w;
  *reinterpret_cast<f16x8*>(xh + i) = h;
}

// sum 8 K-slice partials + bias -> out (4 outputs per thread)
__global__ void reduce_kernel(const float* __restrict__ partial,
                              const float* __restrict__ bias,
                              float* __restrict__ out) {
  const int idx = (blockIdx.x * 256 + threadIdx.x) * 4;   // 344 blocks exact
  const int n = idx % N;                                  // N,idx multiples of 4
  float4 a = *reinterpret_cast<const float4*>(bias + n);
#pragma unroll
  for (int s = 0; s < KSPLIT; ++s) {
    const float4 p = *reinterpret_cast<const float4*>(partial + s * OUT_ELEMS + idx);
    a.x += p.x; a.y += p.y; a.z += p.z; a.w += p.w;
  }
  *reinterpret_cast<float4*>(out + idx) = a;
}

__global__ __launch_bounds__(256) void awq_gemm_kernel(
    const int* __restrict__ qw, const int* __restrict__ qz,
    const float* __restrict__ sc, const _Float16* __restrict__ xh,
    float* __restrict__ partial)
{
  // transposed q tile: [16 word-cols][32 k], stride 34 (even -> aligned b64)
  __shared__ int lq[2][16 * QSTR];

  const int tid  = threadIdx.x;
  const int lane = tid & 63;
  const int wid  = tid >> 6;      // wave 0..3
  const int kq   = lane >> 4;     // 0..3  (k-quarter within MFMA frag)
  const int c16  = lane & 15;     // fragment row/col index

  const int n0 = blockIdx.x * BN;
  const int c0 = n0 >> 3;

  // AWQ nibble shift for col (n&7): 4*AWQ_ORDER[n&7], order [0,4,1,5,2,6,3,7]
  const int j7 = c16 & 7;
  const int sh = ((j7 >> 1) | ((j7 & 1) << 2)) << 2;

  int ncol[2], cglob[2], cloc[2];
#pragma unroll
  for (int t2 = 0; t2 < 2; ++t2) {
    ncol[t2]  = n0 + wid * 32 + t2 * 16 + c16;
    cglob[t2] = ncol[t2] >> 3;
    cloc[t2]  = cglob[t2] - c0;
  }

  const int kbeg = blockIdx.y * (K / KSPLIT);
  const int g0   = kbeg >> 7;     // first quant group of this slice (4 total)

  // ---- prefetch all group scalars (issued up-front, held in regs) ----
  int   zqv[4][2];
  float sfv[4][2];
#pragma unroll
  for (int g = 0; g < 4; ++g)
#pragma unroll
    for (int t2 = 0; t2 < 2; ++t2) {
      zqv[g][t2] = qz[(g0 + g) * NC + cglob[t2]];
      sfv[g][t2] = sc[(g0 + g) * N + ncol[t2]];
    }

  // ---- staging geometry: thread -> (row sr, word-pair so) ----
  const int sr = tid >> 3;        // 0..31 (k within tile)
  const int so = tid & 7;         // 0..7  (word pair)
  const int* qsrc = qw + (long)(kbeg + sr) * NC + c0 + so * 2;
  const int wa0 = (so * 2) * QSTR + sr;
  const int wa1 = (so * 2 + 1) * QSTR + sr;

  int2 qreg[2];
  f16x8 areg[2][2];               // [slot][m-tile]

  const _Float16* xbase = xh + kbeg + kq * 8;

  // ---- prologue: tiles 0,1 in regs; tile0 -> LDS; tile2 issued ----
  qreg[0] = *reinterpret_cast<const int2*>(qsrc);
  qreg[1] = *reinterpret_cast<const int2*>(qsrc + 1 * BK * NC);
  areg[0][0] = *reinterpret_cast<const f16x8*>(xbase + c16 * K);
  areg[0][1] = *reinterpret_cast<const f16x8*>(xbase + (c16 + 16) * K);
  lq[0][wa0] = qreg[0].x;
  lq[0][wa1] = qreg[0].y;
  qreg[0] = *reinterpret_cast<const int2*>(qsrc + 2 * BK * NC);
  __syncthreads();

  f32x4 acc[2][2] = {};           // [m-tile][n-tile]

#pragma unroll
  for (int g = 0; g < 4; ++g) {
    // group constants: mz2 = -(1024+z) exact; s2 = fp16 scale
    f16x2 s2[2], mz2[2];
#pragma unroll
    for (int t2 = 0; t2 < 2; ++t2) {
      const _Float16 s16 = (_Float16)sfv[g][t2];
      const _Float16 mz  = (_Float16)(-(float)(1024 + ((zqv[g][t2] >> sh) & 15)));
      s2[t2][0] = s16; s2[t2][1] = s16;
      mz2[t2][0] = mz; mz2[t2][1] = mz;
    }
#pragma unroll
    for (int tt = 0; tt < 4; ++tt) {
      const int t   = g * 4 + tt;
      const int cur = t & 1;

      // ---- compute step t from lq[cur] + areg[cur] ----
#pragma unroll
      for (int t2 = 0; t2 < 2; ++t2) {
        const int base = cloc[t2] * QSTR + kq * 8;
        f16x8 b;
#pragma unroll
        for (int jj = 0; jj < 4; ++jj) {
          const int2 q01 = *reinterpret_cast<const int2*>(&lq[cur][base + 2 * jj]);
          const unsigned r0 = (((unsigned)q01.x >> sh) & 15u) | 0x6400u;
          const unsigned r1 = (((unsigned)q01.y >> sh) & 15u) | 0x6400u;
          const unsigned h2u = r0 | (r1 << 16);       // {1024+v0, 1024+v1}
          const f16x2 h2 = __builtin_bit_cast(f16x2, h2u);
          const f16x2 w2 = (h2 + mz2[t2]) * s2[t2];   // exact (v-z), then 1 round
          b[2 * jj]     = w2[0];
          b[2 * jj + 1] = w2[1];
        }
        acc[0][t2] = __builtin_amdgcn_mfma_f32_16x16x32_f16(areg[cur][0], b, acc[0][t2], 0, 0, 0);
        acc[1][t2] = __builtin_amdgcn_mfma_f32_16x16x32_f16(areg[cur][1], b, acc[1][t2], 0, 0, 0);
      }

      if (t < NT - 1) {
        // stage tile t+1 (regs -> other LDS buffer)
        lq[cur ^ 1][wa0] = qreg[cur ^ 1].x;
        lq[cur ^ 1][wa1] = qreg[cur ^ 1].y;
        // issue tile t+3 q loads (2-deep) and tile t+1 A loads (1-deep)
        const int tl = (t + 3 < NT) ? (t + 3) : (NT - 1);
        qreg[cur ^ 1] = *reinterpret_cast<const int2*>(qsrc + (long)tl * BK * NC);
        areg[cur ^ 1][0] = *reinterpret_cast<const f16x8*>(xbase + (t + 1) * BK + c16 * K);
        areg[cur ^ 1][1] = *reinterpret_cast<const f16x8*>(xbase + (t + 1) * BK + (c16 + 16) * K);
        __syncthreads();
      }
    }
  }

  // ---- epilogue: plain stores to this slice's partial buffer ----
  float* pp = partial + (long)blockIdx.y * OUT_ELEMS;
#pragma unroll
  for (int mt = 0; mt < 2; ++mt)
#pragma unroll
    for (int t2 = 0; t2 < 2; ++t2)
#pragma unroll
      for (int i = 0; i < 4; ++i) {
        const int row = mt * 16 + kq * 4 + i;
        pp[row * N + ncol[t2]] = acc[mt][t2][i];
      }
}

extern "C" void kernel_launch(void* const* d_in, const int* in_sizes, int n_in,
                              void* d_out, int out_size, void* d_ws, size_t ws_size,
                              hipStream_t stream) {
  const float* x    = (const float*)d_in[0];
  const int* qw     = (const int*)d_in[1];
  const int* qz     = (const int*)d_in[2];
  const float* sc   = (const float*)d_in[3];   // fp16 values delivered as f32
  const float* bias = (const float*)d_in[4];   // fp16 values delivered as f32
  float* out        = (float*)d_out;

  float* partial = (float*)d_ws;                         // 8 x 352256 f32 = 11.3 MB
  _Float16* xh   = (_Float16*)((float*)d_ws + KSPLIT * OUT_ELEMS);  // +256 KB

  cvt_x_kernel<<<dim3((M_ROWS * K) / (256 * 8)), 256, 0, stream>>>(x, xh);
  awq_gemm_kernel<<<dim3(N / BN, KSPLIT), 256, 0, stream>>>(qw, qz, sc, xh, partial);
  reduce_kernel<<<dim3(OUT_ELEMS / (256 * 4)), 256, 0, stream>>>(partial, bias, out);
}